// Round 4
// baseline (3366.256 us; speedup 1.0000x reference)
//
#include <hip/hip_runtime.h>
#include <hip/hip_bf16.h>
#include <cstdint>
#include <cstddef>

// MMDecoderDoubleBranch R10: R9 (zero-barrier wave-private pipeline + DPP GN)
// + staging WAR fences. R9 FAILED (absmax 0.62): global_load_lds writes slot B
// (vmcnt-tracked, lands at data-return) while the previous unit's ds_read of
// slot B (lgkmcnt-tracked) may still be queued -- nothing orders them; hipcc
// sinks MFMAs+lgkmcnt past inline-asm waits (rule #18) and SIInsertWaitcnts
// doesn't model LDS-DMA vs ds_read aliasing. Barriers masked this in R6-R8.
// Fix: before issuing each unit's DMA batch: s_waitcnt lgkmcnt(0) (all prior
// ds_reads have executed) + sched_barrier(0); after the counted vmcnt(N) wait:
// sched_barrier(0) (current ds_reads can't hoist above it). lgkmcnt(0) is
// ~free: the MFMAs consuming the previous fragments already forced it.
// Pipeline recap: 4 waves x 2x5KB private slots, 128 units/step (32 LSTM
// gate-tiles 5KB + 96 mode ct-tiles 4KB), counted vmcnt(5|4) never 0 (t>0);
// NO __syncthreads in the main loop; GN/out-proj/conf reduced with DPP
// row_ror {8,4,2,1} (pure VALU) instead of LDS-pipe shuffles.

#define HD 128
#define TT 30
#define MM 6
#define B_ROWS 32768

typedef _Float16 f16x8 __attribute__((ext_vector_type(8)));
typedef _Float16 f16x4 __attribute__((ext_vector_type(4)));
typedef float f32x4 __attribute__((ext_vector_type(4)));

__device__ __forceinline__ float fast_rcp(float x) { return __builtin_amdgcn_rcpf(x); }
__device__ __forceinline__ float sigm(float x) { return fast_rcp(1.f + __expf(-x)); }
__device__ __forceinline__ float tanhf_(float x) { return 1.f - 2.f * fast_rcp(__expf(2.f * x) + 1.f); }
__device__ __forceinline__ float selu_(float x) {
  const float sc = 1.0507009873554805f;
  const float al = 1.6732632423543772f;
  return x > 0.f ? sc * x : sc * al * (__expf(x) - 1.f);
}

// ---- DPP row (16-lane) sum: every lane gets the sum of its 16-lane group ----
template <int CTRL>
__device__ __forceinline__ float dpp_add(float x) {
  union { float f; int i; } a, b;
  a.f = x;
  b.i = __builtin_amdgcn_update_dpp(a.i, a.i, CTRL, 0xF, 0xF, false);
  return x + b.f;
}
__device__ __forceinline__ float rowsum16(float x) {
  x = dpp_add<0x128>(x);  // row_ror:8
  x = dpp_add<0x124>(x);  // row_ror:4
  x = dpp_add<0x122>(x);  // row_ror:2
  x = dpp_add<0x121>(x);  // row_ror:1
  return x;
}
__device__ __forceinline__ f32x4 rowsum16x4(f32x4 v) {
  v[0] = rowsum16(v[0]); v[1] = rowsum16(v[1]);
  v[2] = rowsum16(v[2]); v[3] = rowsum16(v[3]);
  return v;
}

// ---- weight prep: fragment-ordered f16 ----
// Wg: 32 tiles of 2560 f16, tile index u = cg*4+g (cg-major), inside:
//     [ch=0..4][lane][8].
// W1p/W2p: per mode [ct][ch=0..3][lane][8] (2048 f16 per ct tile);
// cW1p/cW2p: [ct][ch][lane][8].
__global__ __launch_bounds__(256) void prep_weights(
    const float* __restrict__ W_ih, const float* __restrict__ W_hh,
    const float* __restrict__ b_ih, const float* __restrict__ b_hh,
    const float* __restrict__ mW1, const float* __restrict__ mW2,
    const float* __restrict__ cW1, const float* __restrict__ cW2,
    _Float16* __restrict__ Wg, _Float16* __restrict__ W1p, _Float16* __restrict__ W2p,
    _Float16* __restrict__ cW1p, _Float16* __restrict__ cW2p, float* __restrict__ bg) {
  int n = blockIdx.x * 256 + threadIdx.x;
  if (n < 81920) {
    int t16 = n / 2560, r = n % 2560;
    int ch = r / 512, l = (r >> 3) & 63, j = r & 7;
    int q = l >> 4, cl = l & 15;
    int cg = t16 >> 2, g = t16 & 3;            // cg-major tile order
    int row = g * 128 + cg * 16 + cl;          // gate-major output row
    int k = ch * 32 + q * 8 + j;
    float v = 0.f;
    if (k < 128) v = W_hh[row * 128 + k];
    else if (k < 144) v = W_ih[row * 16 + (k - 128)];
    Wg[n] = (_Float16)v;
    return;
  }
  n -= 81920;
  if (n < 98304) {
    int m = n >> 14, r = n & 16383;
    int ct = r >> 11, ch = (r >> 9) & 3, l = (r >> 3) & 63, j = r & 7;
    int q = l >> 4, cl = l & 15;
    int outcol = ct * 16 + cl, k = ch * 32 + q * 8 + j;
    W1p[n] = (_Float16)mW1[(m * 128 + k) * 128 + outcol];
    return;
  }
  n -= 98304;
  if (n < 98304) {
    int m = n >> 14, r = n & 16383;
    int ct = r >> 11, ch = (r >> 9) & 3, l = (r >> 3) & 63, j = r & 7;
    int q = l >> 4, cl = l & 15;
    int outcol = ct * 16 + cl, k = ch * 32 + q * 8 + j;
    W2p[n] = (_Float16)mW2[(m * 128 + k) * 128 + outcol];
    return;
  }
  n -= 98304;
  if (n < 16384) {
    int ct = n >> 11, ch = (n >> 9) & 3, l = (n >> 3) & 63, j = n & 7;
    int q = l >> 4, cl = l & 15;
    int outcol = ct * 16 + cl, k = ch * 32 + q * 8 + j;
    cW1p[n] = (_Float16)cW1[k * 128 + outcol];
    return;
  }
  n -= 16384;
  if (n < 16384) {
    int ct = n >> 11, ch = (n >> 9) & 3, l = (n >> 3) & 63, j = n & 7;
    int q = l >> 4, cl = l & 15;
    int outcol = ct * 16 + cl, k = ch * 32 + q * 8 + j;
    cW2p[n] = (_Float16)cW2[k * 128 + outcol];
    return;
  }
  n -= 16384;
  if (n < 512) bg[n] = b_ih[n] + b_hh[n];
}

__device__ __forceinline__ f32x4 mfma16(f16x8 a, f16x8 b, f32x4 c) {
  return __builtin_amdgcn_mfma_f32_16x16x32_f16(a, b, c, 0, 0, 0);
}

// ---- main decoder: 512 blocks x 4 waves; wave owns 16 rows end-to-end ----
// unit schedule (128/step, same weights every step):
//   u in [0,32):  LSTM gate-tile u -> Wg + u*2560 (5 x 1KB loads)
//   u in [32,128): j=u-32, m=j>>4, k=j&15 -> (k<8?W1p:W2p)+m*16384+(k&7)*2048
//                  (4 x 1KB loads)
__global__ __launch_bounds__(256, 2) void mmdec_main(
    const float* __restrict__ last_obs_rel, const float* __restrict__ h0, const float* __restrict__ c0,
    const float* __restrict__ W_se, const float* __restrict__ b_se,
    const float* __restrict__ mg1w, const float* __restrict__ mg1b,
    const float* __restrict__ mg2w, const float* __restrict__ mg2b,
    const float* __restrict__ mWo, const float* __restrict__ mbo,
    const float* __restrict__ cg1w, const float* __restrict__ cg1b,
    const float* __restrict__ cg2w, const float* __restrict__ cg2b,
    const float* __restrict__ cWo, const float* __restrict__ cbo,
    const _Float16* __restrict__ Wg, const _Float16* __restrict__ W1p, const _Float16* __restrict__ W2p,
    const _Float16* __restrict__ cW1p, const _Float16* __restrict__ cW2p, const float* __restrict__ bgp,
    float* __restrict__ out) {
  // LDS map (bytes): stage 4 waves x 2 x 5120 | h 64x320 | t1 64x272 | rel 64x12 f32
  __shared__ __align__(16) unsigned char smem[81920];
  _Float16* stage0 = (_Float16*)smem;                       // [0, 40960)
  unsigned char* h_base = smem + 40960;                     // [40960, 61440)
  unsigned char* t1_base = smem + 61440;                    // [61440, 78848)
  float* rel_all = (float*)(smem + 78848);                  // [78848, 81920)

  const int tid = threadIdx.x;
  const int w = tid >> 6;       // wave id 0..3: owns rows [16w, 16w+16) of block
  const int lane = tid & 63;
  const int q = lane >> 4, cl = lane & 15;
  const int rowbase = blockIdx.x * 64 + w * 16;             // wave's first global row

  _Float16* stg = stage0 + w * 5120;                        // 2 slots x 2560 f16

  auto hrow = [&](int r) -> _Float16* { return (_Float16*)(h_base + (w * 16 + r) * 320); };
  auto t1row = [&](int r) -> _Float16* { return (_Float16*)(t1_base + (w * 16 + r) * 272); };
  float* relw = rel_all + w * 16 * 12;

  auto gll = [&](const _Float16* s, _Float16* d) {
    __builtin_amdgcn_global_load_lds(
        (const __attribute__((address_space(1))) void*)s,
        (__attribute__((address_space(3))) void*)d, 16, 0, 0);
  };

  // ---- init: h0 -> LDS f16 (quarter row per lane) ----
  {
    const int rr = lane & 15, seg = lane >> 4;
    const float* src = h0 + (size_t)(rowbase + rr) * HD + seg * 32;
    _Float16* dst = hrow(rr) + seg * 32;
#pragma unroll
    for (int i = 0; i < 32; i += 8) {
      f16x8 v;
#pragma unroll
      for (int k = 0; k < 8; ++k) v[k] = (_Float16)src[i + k];
      *(f16x8*)(dst + i) = v;
    }
    // x = selu(tile(last_obs_rel,6) @ W_se.T + b_se); 4 E-cols per lane
    const float r0 = last_obs_rel[(size_t)(rowbase + rr) * 2 + 0];
    const float r1 = last_obs_rel[(size_t)(rowbase + rr) * 2 + 1];
    const int e0 = seg * 4;
    f16x4 v;
#pragma unroll
    for (int i = 0; i < 4; ++i) {
      const int e = e0 + i;
      float acc = b_se[e];
#pragma unroll
      for (int j = 0; j < 12; ++j) acc += ((j & 1) ? r1 : r0) * W_se[e * 12 + j];
      v[i] = (_Float16)selu_(acc);
    }
    *(f16x4*)(hrow(rr) + 128 + e0) = v;
    if (lane < 16) {  // zero pad cols 144..159
      f16x8 z;
#pragma unroll
      for (int i = 0; i < 8; ++i) z[i] = (_Float16)0.f;
      *(f16x8*)(hrow(lane) + 144) = z;
      *(f16x8*)(hrow(lane) + 152) = z;
    }
  }
  // ---- init: c0 in C-layout regs [cg] ----
  f32x4 cacc[8];
#pragma unroll
  for (int cg = 0; cg < 8; ++cg)
#pragma unroll
    for (int r = 0; r < 4; ++r)
      cacc[cg][r] = c0[(size_t)(rowbase + q * 4 + r) * HD + cg * 16 + cl];
  float bgh[8][4];
#pragma unroll
  for (int cg = 0; cg < 8; ++cg)
#pragma unroll
    for (int g = 0; g < 4; ++g) bgh[cg][g] = bgp[g * 128 + cg * 16 + cl];
  f32x4 hc[8];  // h(t) in C-layout (residual source)

  // prologue: stage unit 0 into slot 0 (wave-private; no barrier anywhere)
#pragma unroll
  for (int i = 0; i < 5; ++i) gll(Wg + i * 512 + lane * 8, stg + i * 512 + lane * 8);
  int cur = 0;

  const size_t confbase = (size_t)B_ROWS * MM * TT * 2;

  for (int t = 0; t < TT; ++t) {
    const bool strict = (t == 0);
    int u = 0;
    // Stage unit nu into the other slot, then wait until unit u (current) is
    // resident. WAR fence before the DMA issue: all prior ds_reads must have
    // EXECUTED (lgkmcnt(0)) before new DMA writes can land in their slot;
    // sched_barrier(0) pins MFMAs/ds_reads so the compiler can't move them
    // across (rule #18). Counted vmcnt leaves nu's loads in flight.
    auto advance = [&](int nu) {
      _Float16* dd = stg + ((cur ^ 1) ? 2560 : 0);
      asm volatile("s_waitcnt lgkmcnt(0)" ::: "memory");
      __builtin_amdgcn_sched_barrier(0);
      if (nu < 32) {
        const _Float16* src = Wg + nu * 2560;
#pragma unroll
        for (int i = 0; i < 5; ++i) gll(src + i * 512 + lane * 8, dd + i * 512 + lane * 8);
        if (strict) asm volatile("s_waitcnt vmcnt(0)" ::: "memory");
        else        asm volatile("s_waitcnt vmcnt(5)" ::: "memory");
      } else {
        const int j = nu - 32, mm = j >> 4, k = j & 15;
        const _Float16* src = ((k & 8) ? W2p : W1p) + mm * 16384 + (k & 7) * 2048;
#pragma unroll
        for (int i = 0; i < 4; ++i) gll(src + i * 512 + lane * 8, dd + i * 512 + lane * 8);
        if (strict) asm volatile("s_waitcnt vmcnt(0)" ::: "memory");
        else        asm volatile("s_waitcnt vmcnt(4)" ::: "memory");
      }
      __builtin_amdgcn_sched_barrier(0);
    };

    // ======== LSTM: [h|x|0](K=160) @ Wg^T; c update; h(t) scatter ========
    f16x8 afr[5];
#pragma unroll
    for (int ch = 0; ch < 5; ++ch)
      afr[ch] = *(const f16x8*)(hrow(cl) + ch * 32 + q * 8);

    for (int cg = 0; cg < 8; ++cg) {
      f32x4 gacc[4];
#pragma unroll
      for (int g = 0; g < 4; ++g) {
        advance((u + 1) & 127);
        const _Float16* bp = stg + (cur ? 2560 : 0) + lane * 8;
        f32x4 a = {0.f, 0.f, 0.f, 0.f};
#pragma unroll
        for (int ch = 0; ch < 5; ++ch) {
          f16x8 b = *(const f16x8*)(bp + ch * 512);
          a = mfma16(afr[ch], b, a);
        }
        gacc[g] = a;
        cur ^= 1; ++u;
      }
      // epilogue for cg overlaps the in-flight prefetch of the next unit
#pragma unroll
      for (int r = 0; r < 4; ++r) {
        const float iv = sigm(gacc[0][r] + bgh[cg][0]);
        const float fv = sigm(gacc[1][r] + bgh[cg][1]);
        const float gv = tanhf_(gacc[2][r] + bgh[cg][2]);
        const float ov = sigm(gacc[3][r] + bgh[cg][3]);
        const float cn = fv * cacc[cg][r] + iv * gv;
        cacc[cg][r] = cn;
        const float hv = ov * tanhf_(cn);
        hc[cg][r] = hv;
        hrow(q * 4 + r)[cg * 16 + cl] = (_Float16)hv;
      }
    }

    // ======== 6 mode heads (fully wave-local) ========
    f16x8 frag[4];
#pragma unroll
    for (int ch = 0; ch < 4; ++ch)
      frag[ch] = *(const f16x8*)(hrow(cl) + ch * 32 + q * 8);

    for (int m = 0; m < MM; ++m) {
      f32x4 acc1[8];
#pragma unroll
      for (int ct = 0; ct < 8; ++ct) {
        advance((u + 1) & 127);
        const _Float16* bp = stg + (cur ? 2560 : 0) + lane * 8;
        f32x4 a = {0.f, 0.f, 0.f, 0.f};
#pragma unroll
        for (int ch = 0; ch < 4; ++ch) {
          f16x8 b = *(const f16x8*)(bp + ch * 512);
          a = mfma16(frag[ch], b, a);
        }
        acc1[ct] = a;
        cur ^= 1; ++u;
      }
      // GN1 (DPP) + relu -> t1 (overlaps in-flight W2 ct0 prefetch)
      f32x4 mean, rstd;
      {
        f32x4 s1 = {0.f, 0.f, 0.f, 0.f}, s2 = {0.f, 0.f, 0.f, 0.f};
#pragma unroll
        for (int ct = 0; ct < 8; ++ct) { s1 += acc1[ct]; s2 += acc1[ct] * acc1[ct]; }
        s1 = rowsum16x4(s1); s2 = rowsum16x4(s2);
        mean = s1 * (1.f / 128.f);
#pragma unroll
        for (int r = 0; r < 4; ++r)
          rstd[r] = rsqrtf(s2[r] * (1.f / 128.f) - mean[r] * mean[r] + 1e-5f);
      }
#pragma unroll
      for (int ct = 0; ct < 8; ++ct) {
        const float g1 = mg1w[m * HD + ct * 16 + cl];
        const float b1 = mg1b[m * HD + ct * 16 + cl];
#pragma unroll
        for (int r = 0; r < 4; ++r) {
          float v = (acc1[ct][r] - mean[r]) * rstd[r] * g1 + b1;
          t1row(q * 4 + r)[ct * 16 + cl] = (_Float16)fmaxf(v, 0.f);
        }
      }
      // gemm2 from t1 (same-wave LDS write->read is in-order)
      f16x8 at1[4];
#pragma unroll
      for (int ch = 0; ch < 4; ++ch)
        at1[ch] = *(const f16x8*)(t1row(cl) + ch * 32 + q * 8);
      f32x4 acc2[8];
#pragma unroll
      for (int ct = 0; ct < 8; ++ct) {
        advance((u + 1) & 127);
        const _Float16* bp = stg + (cur ? 2560 : 0) + lane * 8;
        f32x4 a = {0.f, 0.f, 0.f, 0.f};
#pragma unroll
        for (int ch = 0; ch < 4; ++ch) {
          f16x8 b = *(const f16x8*)(bp + ch * 512);
          a = mfma16(at1[ch], b, a);
        }
        acc2[ct] = a;
        cur ^= 1; ++u;
      }
      // GN2 (DPP) + residual (hc regs) + out-proj
      f32x4 mean2, rstd2;
      {
        f32x4 s1 = {0.f, 0.f, 0.f, 0.f}, s2 = {0.f, 0.f, 0.f, 0.f};
#pragma unroll
        for (int ct = 0; ct < 8; ++ct) { s1 += acc2[ct]; s2 += acc2[ct] * acc2[ct]; }
        s1 = rowsum16x4(s1); s2 = rowsum16x4(s2);
        mean2 = s1 * (1.f / 128.f);
#pragma unroll
        for (int r = 0; r < 4; ++r)
          rstd2[r] = rsqrtf(s2[r] * (1.f / 128.f) - mean2[r] * mean2[r] + 1e-5f);
      }
      f32x4 po0 = {0.f, 0.f, 0.f, 0.f}, po1 = {0.f, 0.f, 0.f, 0.f};
#pragma unroll
      for (int ct = 0; ct < 8; ++ct) {
        const float g2 = mg2w[m * HD + ct * 16 + cl];
        const float b2 = mg2b[m * HD + ct * 16 + cl];
        const float w0 = mWo[((size_t)m * HD + ct * 16 + cl) * 2 + 0];
        const float w1 = mWo[((size_t)m * HD + ct * 16 + cl) * 2 + 1];
#pragma unroll
        for (int r = 0; r < 4; ++r) {
          float v = (acc2[ct][r] - mean2[r]) * rstd2[r] * g2 + b2 + hc[ct][r];
          v = fmaxf(v, 0.f);
          po0[r] += v * w0;
          po1[r] += v * w1;
        }
      }
      po0 = rowsum16x4(po0);
      po1 = rowsum16x4(po1);
      if (cl < 2) {
#pragma unroll
        for (int r = 0; r < 4; ++r) {
          const int rl_ = q * 4 + r;
          const float val = (cl ? po1[r] : po0[r]) + mbo[m * 2 + cl];
          out[(((size_t)(rowbase + rl_) * MM + m) * TT + t) * 2 + cl] = val;
          relw[rl_ * 12 + m * 2 + cl] = val;
        }
      }
    }

    // ======== xin = selu(rel @ W_se.T + b_se) -> x cols (wave-local) ========
    {
      const int rr = lane & 15, e0 = (lane >> 4) * 4;
      float rl[12];
#pragma unroll
      for (int j = 0; j < 12; ++j) rl[j] = relw[rr * 12 + j];
      f16x4 v;
#pragma unroll
      for (int i = 0; i < 4; ++i) {
        const int e = e0 + i;
        float acc = b_se[e];
#pragma unroll
        for (int j = 0; j < 12; ++j) acc += rl[j] * W_se[e * 12 + j];
        v[i] = (_Float16)selu_(acc);
      }
      *(f16x4*)(hrow(rr) + 128 + e0) = v;
    }
  }

  // ======== confidence head on hT (wave-local; weights from global) ========
  {
    f16x8 frag[4];
#pragma unroll
    for (int ch = 0; ch < 4; ++ch)
      frag[ch] = *(const f16x8*)(hrow(cl) + ch * 32 + q * 8);
    f32x4 acc1[8];
#pragma unroll
    for (int ct = 0; ct < 8; ++ct) {
      const _Float16* bp = cW1p + ct * 2048 + lane * 8;
      f32x4 a0 = {0.f, 0.f, 0.f, 0.f};
#pragma unroll
      for (int ch = 0; ch < 4; ++ch) {
        f16x8 b = *(const f16x8*)(bp + ch * 512);
        a0 = mfma16(frag[ch], b, a0);
      }
      acc1[ct] = a0;
    }
    f32x4 mean, rstd;
    {
      f32x4 s1 = {0.f, 0.f, 0.f, 0.f}, s2 = {0.f, 0.f, 0.f, 0.f};
#pragma unroll
      for (int ct = 0; ct < 8; ++ct) { s1 += acc1[ct]; s2 += acc1[ct] * acc1[ct]; }
      s1 = rowsum16x4(s1); s2 = rowsum16x4(s2);
      mean = s1 * (1.f / 128.f);
#pragma unroll
      for (int r = 0; r < 4; ++r)
        rstd[r] = rsqrtf(s2[r] * (1.f / 128.f) - mean[r] * mean[r] + 1e-5f);
    }
#pragma unroll
    for (int ct = 0; ct < 8; ++ct) {
      const float g1 = cg1w[ct * 16 + cl];
      const float b1 = cg1b[ct * 16 + cl];
#pragma unroll
      for (int r = 0; r < 4; ++r) {
        float v = (acc1[ct][r] - mean[r]) * rstd[r] * g1 + b1;
        t1row(q * 4 + r)[ct * 16 + cl] = (_Float16)fmaxf(v, 0.f);
      }
    }
    f16x8 at1[4];
#pragma unroll
    for (int ch = 0; ch < 4; ++ch)
      at1[ch] = *(const f16x8*)(t1row(cl) + ch * 32 + q * 8);
    f32x4 acc2[8];
#pragma unroll
    for (int ct = 0; ct < 8; ++ct) {
      const _Float16* bp = cW2p + ct * 2048 + lane * 8;
      f32x4 a0 = {0.f, 0.f, 0.f, 0.f};
#pragma unroll
      for (int ch = 0; ch < 4; ++ch) {
        f16x8 b = *(const f16x8*)(bp + ch * 512);
        a0 = mfma16(at1[ch], b, a0);
      }
      acc2[ct] = a0;
    }
    f32x4 mean2, rstd2;
    {
      f32x4 s1 = {0.f, 0.f, 0.f, 0.f}, s2 = {0.f, 0.f, 0.f, 0.f};
#pragma unroll
      for (int ct = 0; ct < 8; ++ct) { s1 += acc2[ct]; s2 += acc2[ct] * acc2[ct]; }
      s1 = rowsum16x4(s1); s2 = rowsum16x4(s2);
      mean2 = s1 * (1.f / 128.f);
#pragma unroll
      for (int r = 0; r < 4; ++r)
        rstd2[r] = rsqrtf(s2[r] * (1.f / 128.f) - mean2[r] * mean2[r] + 1e-5f);
    }
    float pl[4][6];
#pragma unroll
    for (int r = 0; r < 4; ++r)
#pragma unroll
      for (int k = 0; k < 6; ++k) pl[r][k] = 0.f;
#pragma unroll
    for (int ct = 0; ct < 8; ++ct) {
      const float g2 = cg2w[ct * 16 + cl];
      const float b2 = cg2b[ct * 16 + cl];
      float wo[6];
#pragma unroll
      for (int k = 0; k < 6; ++k) wo[k] = cWo[(ct * 16 + cl) * 6 + k];
#pragma unroll
      for (int r = 0; r < 4; ++r) {
        float v = (acc2[ct][r] - mean2[r]) * rstd2[r] * g2 + b2 + hc[ct][r];
        v = fmaxf(v, 0.f);
#pragma unroll
        for (int k = 0; k < 6; ++k) pl[r][k] += v * wo[k];
      }
    }
#pragma unroll
    for (int r = 0; r < 4; ++r)
#pragma unroll
      for (int k = 0; k < 6; ++k) pl[r][k] = rowsum16(pl[r][k]);
    if (cl == 0) {
#pragma unroll
      for (int r = 0; r < 4; ++r) {
        float l[6];
#pragma unroll
        for (int k = 0; k < 6; ++k) l[k] = pl[r][k] + cbo[k];
        float mx = l[0];
#pragma unroll
        for (int k = 1; k < 6; ++k) mx = fmaxf(mx, l[k]);
        float s = 0.f;
#pragma unroll
        for (int k = 0; k < 6; ++k) { l[k] = __expf(l[k] - mx); s += l[k]; }
        const float inv = fast_rcp(s);
#pragma unroll
        for (int k = 0; k < 6; ++k)
          out[confbase + (size_t)(rowbase + q * 4 + r) * 6 + k] = l[k] * inv;
      }
    }
  }
}

extern "C" void kernel_launch(void* const* d_in, const int* in_sizes, int n_in,
                              void* d_out, int out_size, void* d_ws, size_t ws_size,
                              hipStream_t stream) {
  (void)in_sizes; (void)n_in; (void)out_size; (void)ws_size;
  const float* last_obs_rel = (const float*)d_in[1];
  const float* h0   = (const float*)d_in[2];
  const float* c0   = (const float*)d_in[3];
  const float* W_se = (const float*)d_in[4];
  const float* b_se = (const float*)d_in[5];
  const float* W_ih = (const float*)d_in[6];
  const float* W_hh = (const float*)d_in[7];
  const float* b_ih = (const float*)d_in[8];
  const float* b_hh = (const float*)d_in[9];
  const float* mW1  = (const float*)d_in[10];
  const float* mg1w = (const float*)d_in[11];
  const float* mg1b = (const float*)d_in[12];
  const float* mW2  = (const float*)d_in[13];
  const float* mg2w = (const float*)d_in[14];
  const float* mg2b = (const float*)d_in[15];
  const float* mWo  = (const float*)d_in[16];
  const float* mbo  = (const float*)d_in[17];
  const float* cW1  = (const float*)d_in[18];
  const float* cg1w = (const float*)d_in[19];
  const float* cg1b = (const float*)d_in[20];
  const float* cW2  = (const float*)d_in[21];
  const float* cg2w = (const float*)d_in[22];
  const float* cg2b = (const float*)d_in[23];
  const float* cWo  = (const float*)d_in[24];
  const float* cbo  = (const float*)d_in[25];

  char* ws = (char*)d_ws;
  _Float16* Wg   = (_Float16*)(ws + 0);       // 512*160 f16   = 163840 B
  _Float16* W1p  = (_Float16*)(ws + 163840);  // 6*128*128 f16 = 196608 B
  _Float16* W2p  = (_Float16*)(ws + 360448);  // 6*128*128 f16 = 196608 B
  _Float16* cW1p = (_Float16*)(ws + 557056);  // 128*128 f16   =  32768 B
  _Float16* cW2p = (_Float16*)(ws + 589824);  // 128*128 f16   =  32768 B
  float*    bg   = (float*)   (ws + 622592);  // 512 f32       =   2048 B

  prep_weights<<<1218, 256, 0, stream>>>(W_ih, W_hh, b_ih, b_hh, mW1, mW2, cW1, cW2,
                                         Wg, W1p, W2p, cW1p, cW2p, bg);
  mmdec_main<<<B_ROWS / 64, 256, 0, stream>>>(last_obs_rel, h0, c0, W_se, b_se,
                                              mg1w, mg1b, mg2w, mg2b, mWo, mbo,
                                              cg1w, cg1b, cg2w, cg2b, cWo, cbo,
                                              Wg, W1p, W2p, cW1p, cW2p, bg, (float*)d_out);
}